// Round 4
// baseline (2173.094 us; speedup 1.0000x reference)
//
#include <hip/hip_runtime.h>
#include <hip/hip_bf16.h>

// B=256, S=512, D=128, R=2048, H=0.5
#define Bn 256
#define Sn 512
#define Dn 128
#define Rn 2048
#define TB 16
#define NBLK (Sn / TB)   // 32 time-blocks
#define LDX 136          // Xs LDS row stride (bf16)
#define LDP 2052         // PX LDS row stride (bf16): 2048 + 4
#define LDI 132          // input-stage LDS row stride (fp32)
#define NT 1024          // threads per WG (16 waves)
#define NW 16
#define KHn 1024         // phase-D K half

using bf16_t = __hip_bfloat16;
typedef short bf16x8 __attribute__((ext_vector_type(8)));
typedef float f32x4 __attribute__((ext_vector_type(4)));
typedef float f32x2 __attribute__((ext_vector_type(2)));

__device__ __forceinline__ f32x2 clip2(f32x2 v) {
  v = __builtin_elementwise_max(v, (f32x2)(-5.f));
  v = __builtin_elementwise_min(v, (f32x2)(5.f));
  return v;
}

// fp32 -> bf16 bits, round-to-nearest-even (values finite/clamped here).
__device__ __forceinline__ unsigned bf16rne(float f) {
  const unsigned u = __float_as_uint(f);
  return (u + 0x7fffu + ((u >> 16) & 1u)) >> 16;
}
__device__ __forceinline__ unsigned pack_bf16(f32x2 v) {
  return (bf16rne(v.y) << 16) | (bf16rne(v.x) & 0xffffu);
}

// K0: weights fp32->bf16, zero loss accumulators. Grid covers exactly Rn*Dn.
__global__ __launch_bounds__(256) void k_prep(const float* __restrict__ Wp,
                                              const float* __restrict__ Wr,
                                              bf16_t* __restrict__ Wp_b,
                                              bf16_t* __restrict__ Wr_b,
                                              float* __restrict__ losses) {
  const int i = blockIdx.x * 256 + threadIdx.x;
  Wp_b[i] = __float2bfloat16(Wp[i]);
  Wr_b[i] = __float2bfloat16(Wr[i]);
  if (i == 0) { losses[0] = 0.f; losses[1] = 0.f; }
}

// Fused pipeline, full-R per WG, TB=16: 256 WGs (one per batch), 1024 threads.
// LDS 78.8 KB -> 2 WGs/CU (32 waves/CU): cross-WG phase overlap hides the
// barrier-serial phase chain. No global atomics on preds.
__global__ __launch_bounds__(1024, 8) void k_fused(
    const float* __restrict__ inp,
    const float* __restrict__ om_i, const float* __restrict__ ga_i,
    const float* __restrict__ al_i,
    const bf16_t* __restrict__ Wp, const float* __restrict__ bp,
    const float* __restrict__ omr, const float* __restrict__ gar,
    const float* __restrict__ alr,
    const float* __restrict__ omo, const float* __restrict__ gao,
    const float* __restrict__ alo,
    const bf16_t* __restrict__ Wr, const float* __restrict__ br,
    float* __restrict__ preds, float* __restrict__ losses) {
  __shared__ bf16_t Xs[TB * LDX];     // 4.25 KB
  __shared__ bf16_t PX[TB * LDP];     // 64.1 KB (input stage / proj / x_out)
  __shared__ float PD[8][16][17];     // 8.5 KB phase-D K-half partials
  __shared__ float smi[NW], smo[NW];  // total 78,848 B

  const int tid = threadIdx.x;
  const int b = blockIdx.x;
  const int wv = tid >> 6, lane = tid & 63;
  const int lr = lane & 15, lq = lane >> 4;

  // input oscillator state (threads 0..127 own d = tid)
  float xi = 0.f, yi = 0.f, pc_in = 0.f;
  float w2i = 0.f, g2i = 0.f, ai = 0.f;
  if (tid < Dn) {
    w2i = om_i[tid] * om_i[tid];
    g2i = 2.f * fabsf(ga_i[tid]);
    ai = al_i[tid];
  }
  const float* inpb = inp + (size_t)b * Sn * Dn;

  // reservoir/output oscillator state: thread owns r = tid*2, tid*2+1 (full R).
  const int rl = tid * 2;
  f32x2 xr = (f32x2)0.f, yr = (f32x2)0.f, xo = (f32x2)0.f, yo = (f32x2)0.f;
  f32x2 w2r, g2r, arv, w2o, g2o, aov, bpv;
  {
    f32x2 t;
    t = *(const f32x2*)(omr + rl); w2r = t * t;
    t = *(const f32x2*)(gar + rl); g2r = __builtin_elementwise_abs(t) * 2.f;
    arv = *(const f32x2*)(alr + rl);
    t = *(const f32x2*)(omo + rl); w2o = t * t;
    t = *(const f32x2*)(gao + rl); g2o = __builtin_elementwise_abs(t) * 2.f;
    aov = *(const f32x2*)(alo + rl);
    bpv = *(const f32x2*)(bp + rl);  // proj bias lives in registers, added in C
  }
  f32x2 pc_out2 = (f32x2)0.f;

  // Phase-D constants: wave wv owns (col-tile dj, K-half kh).
  const int dj = wv & 7, kh = wv >> 3, d0 = dj * 16;
  const float bco = br[d0 + lr];  // readout bias, fixed column per lane
  const bf16_t* wr_base = Wr + (size_t)(d0 + lr) * Rn + kh * KHn + lq * 8;

  float* Is = (float*)PX;  // input staging overlay: [TB][LDI] fp32 = 8.25 KB
  const int srow = tid >> 5, sc4 = (tid & 31) * 4;  // valid for tid<512

  // prologue: stage tile 0 into registers (threads 0..511, 1 f32x4 each)
  f32x4 stg = (f32x4)0.f;
  if (tid < 512)
    stg = __builtin_nontemporal_load(
        (const f32x4*)(inpb + (size_t)srow * Dn + sc4));

  __syncthreads();

  for (int blk = 0; blk < NBLK; ++blk) {
    const int t0 = blk * TB;

    // ---- Phase A0: write register-staged input tile -> Is ----
    if (tid < 512) *(f32x4*)&Is[srow * LDI + sc4] = stg;
    __syncthreads();

    // ---- Phase A: input oscillator, 16 steps (threads 0..127) ----
    if (tid < Dn) {
#pragma unroll
      for (int tt = 0; tt < TB; ++tt) {
        const float f = Is[tt * LDI + tid];
        if (t0 + tt > 0) { const float e = xi - f; pc_in += e * e; }
        const float accel = ai * f - g2i * yi - w2i * xi;
        const float xn = fminf(fmaxf(xi + 0.5f * yi, -5.f), 5.f);
        const float yn = fminf(fmaxf(yi + 0.5f * accel, -5.f), 5.f);
        Xs[tt * LDX + tid] = __float2bfloat16(xn);
        xi = xn; yi = yn;
      }
    }
    __syncthreads();  // Xs ready; Is dead -> PX writable

    // ---- Phase B: proj [16 x 2048] = Xs[16x128] @ Wp^T -> PX (bf16, no bias) ----
    {
      bf16x8 af[4];
#pragma unroll
      for (int k = 0; k < 4; ++k)
        af[k] = *(const bf16x8*)&Xs[lr * LDX + k * 32 + lq * 8];

      const int lb = wv * 128;  // wave's 128 r-columns, 8 j-tiles
      const bf16_t* wp_base = Wp + (size_t)(lb + lr) * Dn + lq * 8;
      bf16x8 bf[2][4];
#pragma unroll
      for (int k = 0; k < 4; ++k) {
        bf[0][k] = *(const bf16x8*)(wp_base + (size_t)0 * 16 * Dn + k * 32);
        bf[1][k] = *(const bf16x8*)(wp_base + (size_t)1 * 16 * Dn + k * 32);
      }
      for (int j = 0; j < 8; ++j) {
        const int pb = j & 1;
        f32x4 acc = (f32x4)0.f;
#pragma unroll
        for (int k = 0; k < 4; ++k)
          acc = __builtin_amdgcn_mfma_f32_16x16x32_bf16(af[k], bf[pb][k], acc, 0, 0, 0);
        if (j + 2 < 8) {
#pragma unroll
          for (int k = 0; k < 4; ++k)
            bf[pb][k] = *(const bf16x8*)(wp_base + (size_t)(j + 2) * 16 * Dn + k * 32);
        }
        const int cl = lb + j * 16 + lr;
#pragma unroll
        for (int r = 0; r < 4; ++r)
          PX[(lq * 4 + r) * LDP + cl] = __float2bfloat16(acc[r]);
      }
    }
    __syncthreads();

    // ---- Phase C: reservoir + output oscillators, in place in PX ----
    // (proj bias added here in fp32 from registers)
    {
      unsigned pk = *(unsigned*)&PX[0 * LDP + rl];
      for (int tt = 0; tt < TB; ++tt) {
        unsigned pk_n = pk;
        if (tt + 1 < TB) pk_n = *(unsigned*)&PX[(tt + 1) * LDP + rl];
        f32x2 pv;
        pv.x = __uint_as_float(pk << 16);
        pv.y = __uint_as_float(pk & 0xffff0000u);
        pv += bpv;
        f32x2 acr = arv * pv - g2r * yr - w2r * xr;
        f32x2 xrn = clip2(xr + yr * 0.5f);
        f32x2 yrn = clip2(yr + acr * 0.5f);
        f32x2 aco = aov * xrn - g2o * yo - w2o * xo;
        f32x2 xon = clip2(xo + yo * 0.5f);
        f32x2 yon = clip2(yo + aco * 0.5f);
        f32x2 e = xon - xrn;
        pc_out2 += e * e;
        xr = xrn; yr = yrn; xo = xon; yo = yon;
        *(unsigned*)&PX[tt * LDP + rl] = pack_bf16(xon);
        pk = pk_n;
      }
    }
    __syncthreads();

    // ---- Phase D: preds [16 x 128] = PX[16x2048] @ Wr^T + br ----
    // 16 waves = 8 col-tiles x 2 K-halves; combine halves through PD (LDS).
    {
      if (tid < 512 && blk + 1 < NBLK)
        stg = __builtin_nontemporal_load(
            (const f32x4*)(inpb + (size_t)(t0 + TB) * Dn + (size_t)srow * Dn + sc4));

      f32x4 acc[2] = {(f32x4)0.f, (f32x4)0.f};
      bf16x8 bcur = *(const bf16x8*)(wr_base);
#pragma unroll 2
      for (int k0 = 0; k0 < KHn; k0 += 32) {
        bf16x8 bnxt = bcur;
        if (k0 + 32 < KHn) bnxt = *(const bf16x8*)(wr_base + k0 + 32);
        bf16x8 a = *(const bf16x8*)&PX[lr * LDP + kh * KHn + k0 + lq * 8];
        const int par = (k0 >> 5) & 1;
        acc[par] = __builtin_amdgcn_mfma_f32_16x16x32_bf16(a, bcur, acc[par], 0, 0, 0);
        bcur = bnxt;
      }
      const f32x4 s = acc[0] + acc[1];
      if (kh == 1) {
#pragma unroll
        for (int r = 0; r < 4; ++r) PD[dj][lq * 4 + r][lr] = s[r];
      }
      __syncthreads();  // PD ready; all PX reads for this blk done
      if (kh == 0) {
        float* outb = preds + (size_t)b * Sn * Dn + (size_t)t0 * Dn;
#pragma unroll
        for (int r = 0; r < 4; ++r) {
          const int row = lq * 4 + r;
          const float v = s[r] + PD[dj][row][lr] + bco;
          __builtin_nontemporal_store(v, outb + (size_t)row * Dn + d0 + lr);
        }
      }
    }
    __syncthreads();  // PD reads done; PX free for next iteration's Is overlay
  }

  // ---- loss reduction: one atomicAdd per WG per loss ----
  float vi = pc_in;
  float vo = pc_out2.x + pc_out2.y;
#pragma unroll
  for (int o = 32; o > 0; o >>= 1) {
    vi += __shfl_down(vi, o, 64);
    vo += __shfl_down(vo, o, 64);
  }
  if (lane == 0) { smi[wv] = vi; smo[wv] = vo; }
  __syncthreads();
  if (tid == 0) {
    float si = 0.f, so = 0.f;
#pragma unroll
    for (int w = 0; w < NW; ++w) { si += smi[w]; so += smo[w]; }
    atomicAdd(losses + 0, si * (1.f / ((float)Bn * (float)Dn)));
    atomicAdd(losses + 1, so * (1.f / ((float)Bn * (float)Rn)));
  }
}

extern "C" void kernel_launch(void* const* d_in, const int* in_sizes, int n_in,
                              void* d_out, int out_size, void* d_ws, size_t ws_size,
                              hipStream_t stream) {
  const float* inputs    = (const float*)d_in[0];
  const float* omega_in  = (const float*)d_in[1];
  const float* gamma_in  = (const float*)d_in[2];
  const float* alpha_in  = (const float*)d_in[3];
  const float* W_proj    = (const float*)d_in[4];
  const float* b_proj    = (const float*)d_in[5];
  const float* omega_res = (const float*)d_in[6];
  const float* gamma_res = (const float*)d_in[7];
  const float* alpha_res = (const float*)d_in[8];
  const float* omega_out = (const float*)d_in[9];
  const float* gamma_out = (const float*)d_in[10];
  const float* alpha_out = (const float*)d_in[11];
  const float* W_read    = (const float*)d_in[12];
  const float* b_read    = (const float*)d_in[13];

  float* out = (float*)d_out;
  float* losses = out + (size_t)Bn * Sn * Dn;  // outputs: preds | pc_in | pc_out

  // ws: 1 MB — bf16 copies of the two weight matrices.
  bf16_t* Wp_b = (bf16_t*)d_ws;
  bf16_t* Wr_b = Wp_b + (size_t)Rn * Dn;

  k_prep<<<1024, 256, 0, stream>>>(W_proj, W_read, Wp_b, Wr_b, losses);
  k_fused<<<Bn, NT, 0, stream>>>(inputs, omega_in, gamma_in, alpha_in,
                                 Wp_b, b_proj,
                                 omega_res, gamma_res, alpha_res,
                                 omega_out, gamma_out, alpha_out,
                                 Wr_b, b_read, out, losses);
}

// Round 5
// 699.649 us; speedup vs baseline: 3.1060x; 3.1060x over previous
//
#include <hip/hip_runtime.h>
#include <hip/hip_bf16.h>

// B=256, S=512, D=128, R=2048, H=0.5
#define Bn 256
#define Sn 512
#define Dn 128
#define Rn 2048
#define TB 32
#define NBLK (Sn / TB)   // 16 time-blocks
#define LDX 136          // Xs LDS row stride (bf16)
#define LDPs 1028        // PX LDS row stride (bf16), slice width 1024 + 4
#define RG 1024          // r-slice per workgroup (G=2)

using bf16_t = __hip_bfloat16;
typedef short bf16x8 __attribute__((ext_vector_type(8)));
typedef float f32x4 __attribute__((ext_vector_type(4)));
typedef float f32x2 __attribute__((ext_vector_type(2)));

__device__ __forceinline__ f32x2 clip2(f32x2 v) {
  v = __builtin_elementwise_max(v, (f32x2)(-5.f));
  v = __builtin_elementwise_min(v, (f32x2)(5.f));
  return v;
}

// fp32 -> bf16 bits, round-to-nearest-even (values finite/clamped here).
__device__ __forceinline__ unsigned bf16rne(float f) {
  const unsigned u = __float_as_uint(f);
  return (u + 0x7fffu + ((u >> 16) & 1u)) >> 16;
}
__device__ __forceinline__ unsigned pack_bf16(f32x2 v) {
  return (bf16rne(v.y) << 16) | (bf16rne(v.x) & 0xffffu);
}

// K0: weights fp32->bf16, zero loss accumulators. Grid covers exactly Rn*Dn.
__global__ __launch_bounds__(256) void k_prep(const float* __restrict__ Wp,
                                              const float* __restrict__ Wr,
                                              bf16_t* __restrict__ Wp_b,
                                              bf16_t* __restrict__ Wr_b,
                                              float* __restrict__ losses) {
  const int i = blockIdx.x * 256 + threadIdx.x;
  Wp_b[i] = __float2bfloat16(Wp[i]);
  Wr_b[i] = __float2bfloat16(Wr[i]);
  if (i == 0) { losses[0] = 0.f; losses[1] = 0.f; }
}

// K1: init preds with broadcast bias (atomicAdd target). Grid covers Bn*Sn*Dn/4.
__global__ __launch_bounds__(256) void k_zero(float* __restrict__ preds,
                                              const float* __restrict__ br) {
  const int i = blockIdx.x * 256 + threadIdx.x;  // float4 index
  const f32x4 bv = *(const f32x4*)(br + (i & 31) * 4);
  *((f32x4*)preds + i) = bv;
}

// Fused pipeline: 512 WGs. b = bid&255, g = bid>>8 -> pair (b, b+256) lands on
// the SAME XCD (id mod 8 equal): atomics combine in one L2, inputs shared.
// 2 barriers per time-block:
//   R1: input-osc A(blk) [tid<128, direct global loads] || readout D(blk-1) [all]
//   R2: proj B(blk) -> PX (wave-local cols), then res/out osc C(blk) on the
//       same wave-local slice (no barrier needed between B and C).
// LDS 74.6 KB -> 2 WGs/CU; independent WGs overlap phases across the CU.
__global__ __launch_bounds__(512, 4) void k_fused(
    const float* __restrict__ inp,
    const float* __restrict__ om_i, const float* __restrict__ ga_i,
    const float* __restrict__ al_i,
    const bf16_t* __restrict__ Wp, const float* __restrict__ bp,
    const float* __restrict__ omr, const float* __restrict__ gar,
    const float* __restrict__ alr,
    const float* __restrict__ omo, const float* __restrict__ gao,
    const float* __restrict__ alo,
    const bf16_t* __restrict__ Wr,
    float* __restrict__ preds, float* __restrict__ losses) {
  __shared__ bf16_t Xs[TB * LDX];     // 8.5 KB
  __shared__ bf16_t PX[TB * LDPs];    // 64.25 KB (proj slice / x_out slice)
  __shared__ float smi[8], smo[8];

  const int tid = threadIdx.x;
  const int b = blockIdx.x & 255, g = blockIdx.x >> 8;
  const int rbase = g * RG;
  const int wv = tid >> 6, lane = tid & 63;
  const int lr = lane & 15, lq = lane >> 4;

  // input oscillator state (threads 0..127 own d = tid); duplicated across g.
  float xi = 0.f, yi = 0.f, pc_in = 0.f;
  float w2i = 0.f, g2i = 0.f, ai = 0.f;
  if (tid < Dn) {
    w2i = om_i[tid] * om_i[tid];
    g2i = 2.f * fabsf(ga_i[tid]);
    ai = al_i[tid];
  }
  const float* inpb = inp + (size_t)b * Sn * Dn;

  // reservoir/output oscillator state: thread owns local r = tid*2, tid*2+1.
  // rl == wv*128 + lane*2 -> inside this wave's B output slice (wave-local C).
  const int rl = tid * 2;
  f32x2 xr = (f32x2)0.f, yr = (f32x2)0.f, xo = (f32x2)0.f, yo = (f32x2)0.f;
  f32x2 w2r, g2r, arv, w2o, g2o, aov, bpv;
  {
    f32x2 t;
    t = *(const f32x2*)(omr + rbase + rl); w2r = t * t;
    t = *(const f32x2*)(gar + rbase + rl); g2r = __builtin_elementwise_abs(t) * 2.f;
    arv = *(const f32x2*)(alr + rbase + rl);
    t = *(const f32x2*)(omo + rbase + rl); w2o = t * t;
    t = *(const f32x2*)(gao + rbase + rl); g2o = __builtin_elementwise_abs(t) * 2.f;
    aov = *(const f32x2*)(alo + rbase + rl);
    bpv = *(const f32x2*)(bp + rbase + rl);  // proj bias in regs, added in C
  }
  f32x2 pc_out2 = (f32x2)0.f;

  // Phase-B constants: wave's 128 r-columns, 8 j-tiles.
  const bf16_t* wp_base = Wp + (size_t)(rbase + wv * 128 + lr) * Dn + lq * 8;
  // Phase-D constants: wave wv owns preds col-tile d0, full K-half.
  const int d0 = wv * 16;
  const bf16_t* wr_base = Wr + (size_t)(d0 + lr) * Rn + rbase + lq * 8;

  // Phase D body (readout GEMM for time rows tp0..tp0+31, atomic combine).
  auto phaseD = [&](int tp0) {
    f32x4 acc[2][2] = {{(f32x4)0.f, (f32x4)0.f}, {(f32x4)0.f, (f32x4)0.f}};
    bf16x8 bcur = *(const bf16x8*)(wr_base);
#pragma unroll 2
    for (int k0 = 0; k0 < RG; k0 += 32) {
      bf16x8 bnxt = bcur;
      if (k0 + 32 < RG) bnxt = *(const bf16x8*)(wr_base + k0 + 32);
      const int par = (k0 >> 5) & 1;
      bf16x8 a0 = *(const bf16x8*)&PX[(0 + lr) * LDPs + k0 + lq * 8];
      bf16x8 a1 = *(const bf16x8*)&PX[(16 + lr) * LDPs + k0 + lq * 8];
      acc[0][par] = __builtin_amdgcn_mfma_f32_16x16x32_bf16(a0, bcur, acc[0][par], 0, 0, 0);
      acc[1][par] = __builtin_amdgcn_mfma_f32_16x16x32_bf16(a1, bcur, acc[1][par], 0, 0, 0);
      bcur = bnxt;
    }
    float* outb = preds + (size_t)b * Sn * Dn + (size_t)tp0 * Dn;
#pragma unroll
    for (int i = 0; i < 2; ++i) {
      f32x4 s = acc[i][0] + acc[i][1];
#pragma unroll
      for (int r = 0; r < 4; ++r) {
        const int row = i * 16 + lq * 4 + r;
        atomicAdd(outb + (size_t)row * Dn + d0 + lr, s[r]);
      }
    }
  };

  for (int blk = 0; blk < NBLK; ++blk) {
    const int t0 = blk * TB;

    // ---- R1: input oscillator A(blk) [direct global loads] + D(blk-1) ----
    if (tid < Dn) {
#pragma unroll
      for (int tt = 0; tt < TB; ++tt) {
        const float f = inpb[(size_t)(t0 + tt) * Dn + tid];
        if (t0 + tt > 0) { const float e = xi - f; pc_in += e * e; }
        const float accel = ai * f - g2i * yi - w2i * xi;
        const float xn = fminf(fmaxf(xi + 0.5f * yi, -5.f), 5.f);
        const float yn = fminf(fmaxf(yi + 0.5f * accel, -5.f), 5.f);
        Xs[tt * LDX + tid] = __float2bfloat16(xn);
        xi = xn; yi = yn;
      }
    }
    if (blk > 0) phaseD(t0 - TB);
    __syncthreads();  // Xs ready for B; PX free (D done reading)

    // ---- R2a: proj B(blk): PX[32 x 1024] = Xs[32x128] @ Wp_slice^T ----
    {
      bf16x8 af[2][4];
#pragma unroll
      for (int i = 0; i < 2; ++i)
#pragma unroll
        for (int k = 0; k < 4; ++k)
          af[i][k] = *(const bf16x8*)&Xs[(i * 16 + lr) * LDX + k * 32 + lq * 8];

      bf16x8 bfr[2][4];
#pragma unroll
      for (int k = 0; k < 4; ++k) {
        bfr[0][k] = *(const bf16x8*)(wp_base + (size_t)0 * 16 * Dn + k * 32);
        bfr[1][k] = *(const bf16x8*)(wp_base + (size_t)1 * 16 * Dn + k * 32);
      }
      for (int j = 0; j < 8; ++j) {
        const int pb = j & 1;
        f32x4 acc[2] = {(f32x4)0.f, (f32x4)0.f};
#pragma unroll
        for (int k = 0; k < 4; ++k) {
          acc[0] = __builtin_amdgcn_mfma_f32_16x16x32_bf16(af[0][k], bfr[pb][k], acc[0], 0, 0, 0);
          acc[1] = __builtin_amdgcn_mfma_f32_16x16x32_bf16(af[1][k], bfr[pb][k], acc[1], 0, 0, 0);
        }
        if (j + 2 < 8) {
#pragma unroll
          for (int k = 0; k < 4; ++k)
            bfr[pb][k] = *(const bf16x8*)(wp_base + (size_t)(j + 2) * 16 * Dn + k * 32);
        }
        const int cl = wv * 128 + j * 16 + lr;
#pragma unroll
        for (int i = 0; i < 2; ++i)
#pragma unroll
          for (int r = 0; r < 4; ++r)
            PX[(i * 16 + lq * 4 + r) * LDPs + cl] = __float2bfloat16(acc[i][r]);
      }
    }

    // ---- R2b: res/out oscillators C(blk), wave-local slice of PX ----
    // (no barrier: this wave wrote PX cols [wv*128, wv*128+128) above;
    //  compiler-inserted lgkmcnt orders the ds_write -> ds_read chain)
    {
      unsigned pk = *(unsigned*)&PX[0 * LDPs + rl];
      for (int tt = 0; tt < TB; ++tt) {
        unsigned pk_n = pk;
        if (tt + 1 < TB) pk_n = *(unsigned*)&PX[(tt + 1) * LDPs + rl];
        f32x2 pv;
        pv.x = __uint_as_float(pk << 16);
        pv.y = __uint_as_float(pk & 0xffff0000u);
        pv += bpv;
        f32x2 acr = arv * pv - g2r * yr - w2r * xr;
        f32x2 xrn = clip2(xr + yr * 0.5f);
        f32x2 yrn = clip2(yr + acr * 0.5f);
        f32x2 aco = aov * xrn - g2o * yo - w2o * xo;
        f32x2 xon = clip2(xo + yo * 0.5f);
        f32x2 yon = clip2(yo + aco * 0.5f);
        f32x2 e = xon - xrn;
        pc_out2 += e * e;
        xr = xrn; yr = yrn; xo = xon; yo = yon;
        *(unsigned*)&PX[tt * LDPs + rl] = pack_bf16(xon);
        pk = pk_n;
      }
    }
    __syncthreads();  // x_out slice ready for next R1's D
  }

  // ---- epilogue: final readout D(NBLK-1) ----
  phaseD(Sn - TB);

  // ---- loss reduction: one atomicAdd per block per loss ----
  float vi = pc_in;
  float vo = pc_out2.x + pc_out2.y;
#pragma unroll
  for (int o = 32; o > 0; o >>= 1) {
    vi += __shfl_down(vi, o, 64);
    vo += __shfl_down(vo, o, 64);
  }
  if (lane == 0) { smi[wv] = vi; smo[wv] = vo; }
  __syncthreads();
  if (tid == 0) {
    float si = 0.f, so = 0.f;
#pragma unroll
    for (int w = 0; w < 8; ++w) { si += smi[w]; so += smo[w]; }
    if (g == 0) atomicAdd(losses + 0, si * (1.f / ((float)Bn * (float)Dn)));
    atomicAdd(losses + 1, so * (1.f / ((float)Bn * (float)Rn)));
  }
}

extern "C" void kernel_launch(void* const* d_in, const int* in_sizes, int n_in,
                              void* d_out, int out_size, void* d_ws, size_t ws_size,
                              hipStream_t stream) {
  const float* inputs    = (const float*)d_in[0];
  const float* omega_in  = (const float*)d_in[1];
  const float* gamma_in  = (const float*)d_in[2];
  const float* alpha_in  = (const float*)d_in[3];
  const float* W_proj    = (const float*)d_in[4];
  const float* b_proj    = (const float*)d_in[5];
  const float* omega_res = (const float*)d_in[6];
  const float* gamma_res = (const float*)d_in[7];
  const float* alpha_res = (const float*)d_in[8];
  const float* omega_out = (const float*)d_in[9];
  const float* gamma_out = (const float*)d_in[10];
  const float* alpha_out = (const float*)d_in[11];
  const float* W_read    = (const float*)d_in[12];
  const float* b_read    = (const float*)d_in[13];

  float* out = (float*)d_out;
  float* losses = out + (size_t)Bn * Sn * Dn;  // outputs: preds | pc_in | pc_out

  // ws: only 1 MB needed — bf16 copies of the two weight matrices.
  bf16_t* Wp_b = (bf16_t*)d_ws;
  bf16_t* Wr_b = Wp_b + (size_t)Rn * Dn;

  k_prep<<<1024, 256, 0, stream>>>(W_proj, W_read, Wp_b, Wr_b, losses);
  k_zero<<<(Bn * Sn * Dn / 4) / 256, 256, 0, stream>>>(out, b_read);
  k_fused<<<Bn * 2, 512, 0, stream>>>(inputs, omega_in, gamma_in, alpha_in,
                                      Wp_b, b_proj,
                                      omega_res, gamma_res, alpha_res,
                                      omega_out, gamma_out, alpha_out,
                                      Wr_b, out, losses);
}

// Round 7
// 698.853 us; speedup vs baseline: 3.1095x; 1.0011x over previous
//
#include <hip/hip_runtime.h>
#include <hip/hip_bf16.h>

// B=256, S=512, D=128, R=2048, H=0.5
#define Bn 256
#define Sn 512
#define Dn 128
#define Rn 2048
#define TB 32
#define NBLK (Sn / TB)   // 16 time-blocks
#define LDX 136          // Xs LDS row stride (bf16)
#define LDPs 1028        // PX LDS row stride (bf16), slice width 1024 + 4
#define RG 1024          // r-slice per workgroup (G=2)

using bf16_t = __hip_bfloat16;
typedef short bf16x8 __attribute__((ext_vector_type(8)));
typedef float f32x4 __attribute__((ext_vector_type(4)));
typedef float f32x2 __attribute__((ext_vector_type(2)));

__device__ __forceinline__ f32x2 clip2(f32x2 v) {
  v = __builtin_elementwise_max(v, (f32x2)(-5.f));
  v = __builtin_elementwise_min(v, (f32x2)(5.f));
  return v;
}

// fp32 -> bf16 bits, round-to-nearest-even (values finite/clamped here).
__device__ __forceinline__ unsigned bf16rne(float f) {
  const unsigned u = __float_as_uint(f);
  return (u + 0x7fffu + ((u >> 16) & 1u)) >> 16;
}
__device__ __forceinline__ unsigned pack_bf16(f32x2 v) {
  return (bf16rne(v.y) << 16) | (bf16rne(v.x) & 0xffffu);
}

// K0: weights fp32->bf16, zero loss accumulators. Grid covers exactly Rn*Dn.
__global__ __launch_bounds__(256) void k_prep(const float* __restrict__ Wp,
                                              const float* __restrict__ Wr,
                                              bf16_t* __restrict__ Wp_b,
                                              bf16_t* __restrict__ Wr_b,
                                              float* __restrict__ losses) {
  const int i = blockIdx.x * 256 + threadIdx.x;
  Wp_b[i] = __float2bfloat16(Wp[i]);
  Wr_b[i] = __float2bfloat16(Wr[i]);
  if (i == 0) { losses[0] = 0.f; losses[1] = 0.f; }
}

// K1 (atomic-fallback only): init preds with broadcast bias.
__global__ __launch_bounds__(256) void k_zero(float* __restrict__ preds,
                                              const float* __restrict__ br) {
  const int i = blockIdx.x * 256 + threadIdx.x;  // float4 index
  const f32x4 bv = *(const f32x4*)(br + (i & 31) * 4);
  *((f32x4*)preds + i) = bv;
}

// K2 (split mode): preds = preds_part0 + part1 + bias.
__global__ __launch_bounds__(256) void k_combine(float* __restrict__ out,
                                                 const float* __restrict__ part,
                                                 const float* __restrict__ br) {
  const int i = blockIdx.x * 256 + threadIdx.x;  // float4 index
  const f32x4 bv = *(const f32x4*)(br + (i & 31) * 4);
  const f32x4 a = *((const f32x4*)out + i);
  const f32x4 p = *((const f32x4*)part + i);
  *((f32x4*)out + i) = a + p + bv;
}

// Fused pipeline: 512 WGs. b = bid&255, g = bid>>8 -> pair (b, b+256) lands on
// the SAME XCD (id mod 8 equal): inputs shared in one L2.
// 2 barriers per time-block:
//   R1: input-osc A(blk) [tid<128, direct global loads] || readout D(blk-1) [all]
//   R2: proj B(blk) -> PX (wave-local cols), then res/out osc C(blk) on the
//       same wave-local slice (no barrier needed between B and C).
// LDS 74.6 KB -> 2 WGs/CU; independent WGs overlap phases across the CU.
// SPLIT=1: phase D writes partial sums (g=0 -> preds, g=1 -> part), combined by
// k_combine. SPLIT=0: atomicAdd into pre-biased preds (fallback, small ws).
template <int SPLIT>
__global__ __launch_bounds__(512, 4) void k_fused(
    const float* __restrict__ inp,
    const float* __restrict__ om_i, const float* __restrict__ ga_i,
    const float* __restrict__ al_i,
    const bf16_t* __restrict__ Wp, const float* __restrict__ bp,
    const float* __restrict__ omr, const float* __restrict__ gar,
    const float* __restrict__ alr,
    const float* __restrict__ omo, const float* __restrict__ gao,
    const float* __restrict__ alo,
    const bf16_t* __restrict__ Wr,
    float* __restrict__ preds, float* __restrict__ part,
    float* __restrict__ losses) {
  __shared__ bf16_t Xs[TB * LDX];     // 8.5 KB
  __shared__ bf16_t PX[TB * LDPs];    // 64.25 KB (proj slice / x_out slice)
  __shared__ float smi[8], smo[8];

  const int tid = threadIdx.x;
  const int b = blockIdx.x & 255, g = blockIdx.x >> 8;
  const int rbase = g * RG;
  const int wv = tid >> 6, lane = tid & 63;
  const int lr = lane & 15, lq = lane >> 4;

  // input oscillator state (threads 0..127 own d = tid); duplicated across g.
  float xi = 0.f, yi = 0.f, pc_in = 0.f;
  float w2i = 0.f, g2i = 0.f, ai = 0.f;
  if (tid < Dn) {
    w2i = om_i[tid] * om_i[tid];
    g2i = 2.f * fabsf(ga_i[tid]);
    ai = al_i[tid];
  }
  const float* inpb = inp + (size_t)b * Sn * Dn;

  // reservoir/output oscillator state: thread owns local r = tid*2, tid*2+1.
  // rl == wv*128 + lane*2 -> inside this wave's B output slice (wave-local C).
  const int rl = tid * 2;
  f32x2 xr = (f32x2)0.f, yr = (f32x2)0.f, xo = (f32x2)0.f, yo = (f32x2)0.f;
  f32x2 w2r, g2r, arv, w2o, g2o, aov, bpv;
  {
    f32x2 t;
    t = *(const f32x2*)(omr + rbase + rl); w2r = t * t;
    t = *(const f32x2*)(gar + rbase + rl); g2r = __builtin_elementwise_abs(t) * 2.f;
    arv = *(const f32x2*)(alr + rbase + rl);
    t = *(const f32x2*)(omo + rbase + rl); w2o = t * t;
    t = *(const f32x2*)(gao + rbase + rl); g2o = __builtin_elementwise_abs(t) * 2.f;
    aov = *(const f32x2*)(alo + rbase + rl);
    bpv = *(const f32x2*)(bp + rbase + rl);  // proj bias in regs, added in C
  }
  f32x2 pc_out2 = (f32x2)0.f;

  // Phase-B constants: wave's 128 r-columns, 8 j-tiles.
  const bf16_t* wp_base = Wp + (size_t)(rbase + wv * 128 + lr) * Dn + lq * 8;
  // Phase-D constants: wave wv owns preds col-tile d0, full K-slice.
  const int d0 = wv * 16;
  const bf16_t* wr_base = Wr + (size_t)(d0 + lr) * Rn + rbase + lq * 8;
  float* pout = (SPLIT && g) ? part : preds;

  // Phase D body (readout GEMM for time rows tp0..tp0+31).
  // Weight stream prefetched depth-4 (ring, static reg indices via 4x unroll).
  auto phaseD = [&](int tp0) {
    f32x4 acc[2][2] = {{(f32x4)0.f, (f32x4)0.f}, {(f32x4)0.f, (f32x4)0.f}};
    bf16x8 bq0 = *(const bf16x8*)(wr_base + 0);
    bf16x8 bq1 = *(const bf16x8*)(wr_base + 32);
    bf16x8 bq2 = *(const bf16x8*)(wr_base + 64);
    bf16x8 bq3 = *(const bf16x8*)(wr_base + 96);
#define DSTEP(BQ, K0, PAR)                                                     \
  {                                                                            \
    bf16x8 a0 = *(const bf16x8*)&PX[(0 + lr) * LDPs + (K0) + lq * 8];          \
    bf16x8 a1 = *(const bf16x8*)&PX[(16 + lr) * LDPs + (K0) + lq * 8];         \
    acc[0][PAR] =                                                              \
        __builtin_amdgcn_mfma_f32_16x16x32_bf16(a0, BQ, acc[0][PAR], 0, 0, 0); \
    acc[1][PAR] =                                                              \
        __builtin_amdgcn_mfma_f32_16x16x32_bf16(a1, BQ, acc[1][PAR], 0, 0, 0); \
    if ((K0) + 128 < RG) BQ = *(const bf16x8*)(wr_base + (K0) + 128);          \
  }
    for (int k0 = 0; k0 < RG; k0 += 128) {
      DSTEP(bq0, k0 + 0, 0)
      DSTEP(bq1, k0 + 32, 1)
      DSTEP(bq2, k0 + 64, 0)
      DSTEP(bq3, k0 + 96, 1)
    }
#undef DSTEP
    float* outb = pout + (size_t)b * Sn * Dn + (size_t)tp0 * Dn;
#pragma unroll
    for (int i = 0; i < 2; ++i) {
      f32x4 s = acc[i][0] + acc[i][1];
#pragma unroll
      for (int r = 0; r < 4; ++r) {
        const int row = i * 16 + lq * 4 + r;
        if (SPLIT)
          __builtin_nontemporal_store(s[r], outb + (size_t)row * Dn + d0 + lr);
        else
          atomicAdd(outb + (size_t)row * Dn + d0 + lr, s[r]);
      }
    }
  };

  for (int blk = 0; blk < NBLK; ++blk) {
    const int t0 = blk * TB;

    // ---- R1: input oscillator A(blk) [direct global loads] + D(blk-1) ----
    if (tid < Dn) {
#pragma unroll
      for (int tt = 0; tt < TB; ++tt) {
        const float f = inpb[(size_t)(t0 + tt) * Dn + tid];
        if (t0 + tt > 0) { const float e = xi - f; pc_in += e * e; }
        const float accel = ai * f - g2i * yi - w2i * xi;
        const float xn = fminf(fmaxf(xi + 0.5f * yi, -5.f), 5.f);
        const float yn = fminf(fmaxf(yi + 0.5f * accel, -5.f), 5.f);
        Xs[tt * LDX + tid] = __float2bfloat16(xn);
        xi = xn; yi = yn;
      }
    }
    if (blk > 0) phaseD(t0 - TB);
    __syncthreads();  // Xs ready for B; PX free (D done reading)

    // ---- R2a: proj B(blk): PX[32 x 1024] = Xs[32x128] @ Wp_slice^T ----
    {
      bf16x8 af[2][4];
#pragma unroll
      for (int i = 0; i < 2; ++i)
#pragma unroll
        for (int k = 0; k < 4; ++k)
          af[i][k] = *(const bf16x8*)&Xs[(i * 16 + lr) * LDX + k * 32 + lq * 8];

      bf16x8 bfr[2][4];
#pragma unroll
      for (int k = 0; k < 4; ++k) {
        bfr[0][k] = *(const bf16x8*)(wp_base + (size_t)0 * 16 * Dn + k * 32);
        bfr[1][k] = *(const bf16x8*)(wp_base + (size_t)1 * 16 * Dn + k * 32);
      }
      for (int j = 0; j < 8; ++j) {
        const int pb = j & 1;
        f32x4 acc[2] = {(f32x4)0.f, (f32x4)0.f};
#pragma unroll
        for (int k = 0; k < 4; ++k) {
          acc[0] = __builtin_amdgcn_mfma_f32_16x16x32_bf16(af[0][k], bfr[pb][k], acc[0], 0, 0, 0);
          acc[1] = __builtin_amdgcn_mfma_f32_16x16x32_bf16(af[1][k], bfr[pb][k], acc[1], 0, 0, 0);
        }
        if (j + 2 < 8) {
#pragma unroll
          for (int k = 0; k < 4; ++k)
            bfr[pb][k] = *(const bf16x8*)(wp_base + (size_t)(j + 2) * 16 * Dn + k * 32);
        }
        const int cl = wv * 128 + j * 16 + lr;
#pragma unroll
        for (int i = 0; i < 2; ++i)
#pragma unroll
          for (int r = 0; r < 4; ++r)
            PX[(i * 16 + lq * 4 + r) * LDPs + cl] = __float2bfloat16(acc[i][r]);
      }
    }

    // ---- R2b: res/out oscillators C(blk), wave-local slice of PX ----
    // (no barrier: this wave wrote PX cols [wv*128, wv*128+128) above;
    //  compiler-inserted lgkmcnt orders the ds_write -> ds_read chain)
    {
      unsigned pk = *(unsigned*)&PX[0 * LDPs + rl];
      for (int tt = 0; tt < TB; ++tt) {
        unsigned pk_n = pk;
        if (tt + 1 < TB) pk_n = *(unsigned*)&PX[(tt + 1) * LDPs + rl];
        f32x2 pv;
        pv.x = __uint_as_float(pk << 16);
        pv.y = __uint_as_float(pk & 0xffff0000u);
        pv += bpv;
        f32x2 acr = arv * pv - g2r * yr - w2r * xr;
        f32x2 xrn = clip2(xr + yr * 0.5f);
        f32x2 yrn = clip2(yr + acr * 0.5f);
        f32x2 aco = aov * xrn - g2o * yo - w2o * xo;
        f32x2 xon = clip2(xo + yo * 0.5f);
        f32x2 yon = clip2(yo + aco * 0.5f);
        f32x2 e = xon - xrn;
        pc_out2 += e * e;
        xr = xrn; yr = yrn; xo = xon; yo = yon;
        *(unsigned*)&PX[tt * LDPs + rl] = pack_bf16(xon);
        pk = pk_n;
      }
    }
    __syncthreads();  // x_out slice ready for next R1's D
  }

  // ---- epilogue: final readout D(NBLK-1) ----
  phaseD(Sn - TB);

  // ---- loss reduction: one atomicAdd per block per loss ----
  float vi = pc_in;
  float vo = pc_out2.x + pc_out2.y;
#pragma unroll
  for (int o = 32; o > 0; o >>= 1) {
    vi += __shfl_down(vi, o, 64);
    vo += __shfl_down(vo, o, 64);
  }
  if (lane == 0) { smi[wv] = vi; smo[wv] = vo; }
  __syncthreads();
  if (tid == 0) {
    float si = 0.f, so = 0.f;
#pragma unroll
    for (int w = 0; w < 8; ++w) { si += smi[w]; so += smo[w]; }
    if (g == 0) atomicAdd(losses + 0, si * (1.f / ((float)Bn * (float)Dn)));
    atomicAdd(losses + 1, so * (1.f / ((float)Bn * (float)Rn)));
  }
}

extern "C" void kernel_launch(void* const* d_in, const int* in_sizes, int n_in,
                              void* d_out, int out_size, void* d_ws, size_t ws_size,
                              hipStream_t stream) {
  const float* inputs    = (const float*)d_in[0];
  const float* omega_in  = (const float*)d_in[1];
  const float* gamma_in  = (const float*)d_in[2];
  const float* alpha_in  = (const float*)d_in[3];
  const float* W_proj    = (const float*)d_in[4];
  const float* b_proj    = (const float*)d_in[5];
  const float* omega_res = (const float*)d_in[6];
  const float* gamma_res = (const float*)d_in[7];
  const float* alpha_res = (const float*)d_in[8];
  const float* omega_out = (const float*)d_in[9];
  const float* gamma_out = (const float*)d_in[10];
  const float* alpha_out = (const float*)d_in[11];
  const float* W_read    = (const float*)d_in[12];
  const float* b_read    = (const float*)d_in[13];

  float* out = (float*)d_out;
  float* losses = out + (size_t)Bn * Sn * Dn;  // outputs: preds | pc_in | pc_out

  // ws layout: [Wp_b 512KB][Wr_b 512KB][partial preds 64MB (split mode)]
  bf16_t* Wp_b = (bf16_t*)d_ws;
  bf16_t* Wr_b = Wp_b + (size_t)Rn * Dn;
  float* part = (float*)(Wr_b + (size_t)Rn * Dn);

  const size_t need = 2u * Rn * Dn * sizeof(bf16_t) +
                      (size_t)Bn * Sn * Dn * sizeof(float);
  const bool split = ws_size >= need;

  k_prep<<<1024, 256, 0, stream>>>(W_proj, W_read, Wp_b, Wr_b, losses);
  if (split) {
    k_fused<1><<<Bn * 2, 512, 0, stream>>>(inputs, omega_in, gamma_in, alpha_in,
                                           Wp_b, b_proj,
                                           omega_res, gamma_res, alpha_res,
                                           omega_out, gamma_out, alpha_out,
                                           Wr_b, out, part, losses);
    k_combine<<<(Bn * Sn * Dn / 4) / 256, 256, 0, stream>>>(out, part, b_read);
  } else {
    k_zero<<<(Bn * Sn * Dn / 4) / 256, 256, 0, stream>>>(out, b_read);
    k_fused<0><<<Bn * 2, 512, 0, stream>>>(inputs, omega_in, gamma_in, alpha_in,
                                           Wp_b, b_proj,
                                           omega_res, gamma_res, alpha_res,
                                           omega_out, gamma_out, alpha_out,
                                           Wr_b, out, part, losses);
  }
}